// Round 5
// baseline (217.779 us; speedup 1.0000x reference)
//
#include <hip/hip_runtime.h>
#include <hip/hip_bf16.h>

#define B_   64
#define N_   1024
#define IND_ 128
#define HID_ 32

typedef __attribute__((ext_vector_type(8))) short short8;
typedef __attribute__((ext_vector_type(4))) float f32x4;
typedef unsigned short u16;

// fp32 -> bf16 RNE via hardware v_cvt_pk_bf16_f32 (see §5.5 T12/m240:
// casts/intrinsics compile to cvt_pk; hand-rolled integer RNE is ~6 VALU
// ops/element and made agg1 VALU-bound)
static __device__ __forceinline__ u16 f2bf(float f) {
    union { __hip_bfloat16 h; u16 s; } u;
    u.h = __float2bfloat16(f);
    return u.s;
}
static __device__ __forceinline__ short8 cvt8(f32x4 v0, f32x4 v1) {
    union { short8 s; __hip_bfloat162 h[4]; } u;
    u.h[0] = __float22bfloat162_rn(float2{v0[0], v0[1]});
    u.h[1] = __float22bfloat162_rn(float2{v0[2], v0[3]});
    u.h[2] = __float22bfloat162_rn(float2{v1[0], v1[1]});
    u.h[3] = __float22bfloat162_rn(float2{v1[2], v1[3]});
    return u.s;
}

// ---------------- linear: hlinT[b][o][n] = sum_f in[b][n][f] * W[f][o] ------
template<int F>
__global__ __launch_bounds__(256) void linear_kernel(
    const float* __restrict__ in,    // [B][N][F] fp32
    const float* __restrict__ W,     // [F][HID]
    u16* __restrict__ outT)          // [B][HID][N] bf16
{
    __shared__ float sW[F][HID_];
    const int tid = threadIdx.x;
    for (int e = tid; e < F * HID_; e += 256) sW[e / HID_][e % HID_] = W[e];
    __syncthreads();

    const int b = blockIdx.x >> 2;
    const int n = ((blockIdx.x & 3) << 8) + tid;
    const f32x4* row4 = (const f32x4*)(in + ((size_t)b * N_ + n) * F);

    float acc[HID_];
#pragma unroll
    for (int o = 0; o < HID_; ++o) acc[o] = 0.f;

#pragma unroll 4
    for (int f4 = 0; f4 < F / 4; ++f4) {
        f32x4 xv = row4[f4];
#pragma unroll
        for (int j = 0; j < 4; ++j) {
#pragma unroll
            for (int o = 0; o < HID_; ++o) acc[o] += xv[j] * sW[f4 * 4 + j][o];
        }
    }
    u16* op = outT + (size_t)b * HID_ * N_ + n;
#pragma unroll
    for (int o = 0; o < HID_; ++o) op[o * N_] = f2bf(acc[o]);
}

// ---------------- aggregation: h = PReLU(adj @ hlin + bias); optional fused
// next-layer linear: hlinT_out = (h @ Wnext)^T in bf16.
// Geometry: 1024 blocks (16 x-tiles x 64 batches), 4 waves/block, 16 rows/wave
//   -> 4096 waves (4/SIMD), ~34KB LDS -> 4 blocks/CU.
// MODE 0: read bf16 adj; MODE 1: read fp32 adj (nt), write bf16 copy;
// MODE 2: read fp32 adj (nt) only, write h to global (fallback path)
template<int MODE, int FUSE>
__global__ __launch_bounds__(256) void agg_kernel(
    const float* __restrict__ adjf,     // [B][N][N] fp32   (MODE 1,2)
    const u16*  __restrict__ adjb_in,   // [B][N][N] bf16   (MODE 0)
    u16*        __restrict__ adjb_out,  // [B][N][N] bf16   (MODE 1)
    const u16*  __restrict__ hlinT_in,  // [B][HID][N] bf16
    u16*        __restrict__ hlinT_out, // [B][HID][N] bf16 (FUSE)
    const float* __restrict__ Wnext,    // [HID][HID]       (FUSE)
    float*      __restrict__ h,         // [B][N][HID] fp32 (MODE 2 only)
    float*      __restrict__ partial,   // [B][16][HID] (this layer's slice)
    const float* __restrict__ bias,     // [HID]
    const float* __restrict__ alpha_p)  // [1]
{
    union Smem {
        u16 sB[HID_][512 + 8];                       // 33,280 B (K-chunk of B)
        struct { float h_s[64][33]; float sW2[HID_][HID_]; } ep;  // 12,544 B
    };
    __shared__ Smem sm;
    __shared__ float pool[4][HID_];

    const int tid = threadIdx.x;
    const int b = blockIdx.y;
    const int wid = tid >> 6, lane = tid & 63;
    const int r16 = lane & 15, g = lane >> 4;
    const int koff = g * 8;
    const int rowbase = blockIdx.x * 64 + wid * 16;
    const int row0 = rowbase + r16;
    const size_t adj_b = (size_t)b * N_ * N_;
    const u16* srcB = hlinT_in + (size_t)b * HID_ * N_;

    const u16*  pa = adjb_in  ? adjb_in  + adj_b + (size_t)row0 * N_ + koff : nullptr;
    const float* pf = adjf    ? adjf     + adj_b + (size_t)row0 * N_ + koff : nullptr;
    u16*        po = adjb_out ? adjb_out + adj_b + (size_t)row0 * N_ + koff : nullptr;

    f32x4 acc[2] = {};

    for (int c = 0; c < 2; ++c) {
        if (c) __syncthreads();          // previous chunk's ds_reads complete
        // stage B chunk: 32 rows x 512 cols bf16 (L2-hot source)
        for (int i = tid; i < 2048; i += 256) {
            const int row = i >> 6;
            const int kv = (i & 63) << 3;
            *(short8*)&sm.sB[row][kv] =
                *(const short8*)(srcB + (size_t)row * N_ + (c << 9) + kv);
        }
        __syncthreads();

#pragma unroll 8
        for (int kk = 0; kk < 512; kk += 32) {
            const int k0 = (c << 9) + kk;
            short8 a0;
            if (MODE == 0) {
                a0 = *(const short8*)(pa + k0);
            } else {
                // non-temporal: keep the dead fp32 stream from evicting the
                // bf16 adj copy needed by layers 2-4
                f32x4 v0 = __builtin_nontemporal_load((const f32x4*)(pf + k0));
                f32x4 v1 = __builtin_nontemporal_load((const f32x4*)(pf + k0) + 1);
                a0 = cvt8(v0, v1);
                if (MODE == 1) *(short8*)(po + k0) = a0;
            }
            short8 b0 = *(const short8*)&sm.sB[r16][kk + koff];
            short8 b1 = *(const short8*)&sm.sB[16 + r16][kk + koff];
            acc[0] = __builtin_amdgcn_mfma_f32_16x16x32_bf16(a0, b0, acc[0], 0, 0, 0);
            acc[1] = __builtin_amdgcn_mfma_f32_16x16x32_bf16(a0, b1, acc[1], 0, 0, 0);
        }
    }

    // bias + PReLU in registers, per-column pool partials
    const float alpha = *alpha_p;
    float v[2][4];
    float ps[2];
#pragma unroll
    for (int ct = 0; ct < 2; ++ct) {
        const float bv = bias[ct * 16 + r16];
        ps[ct] = 0.f;
#pragma unroll
        for (int r = 0; r < 4; ++r) {
            float x = acc[ct][r] + bv;
            x = (x >= 0.f) ? x : alpha * x;
            v[ct][r] = x;
            ps[ct] += x;
        }
    }

    __syncthreads();                     // sB dead; ep space usable

#pragma unroll
    for (int ct = 0; ct < 2; ++ct) {
        const int col = ct * 16 + r16;
        float p = ps[ct];
        p += __shfl_xor(p, 16, 64);
        p += __shfl_xor(p, 32, 64);
        if (lane < 16) pool[wid][col] = p;
        if (FUSE) {
#pragma unroll
            for (int r = 0; r < 4; ++r)
                sm.ep.h_s[wid * 16 + g * 4 + r][col] = v[ct][r];
        }
        if (MODE == 2) {
#pragma unroll
            for (int r = 0; r < 4; ++r) {
                const int row = rowbase + g * 4 + r;
                h[((size_t)b * N_ + row) * HID_ + col] = v[ct][r];
            }
        }
    }
    if (FUSE) {
        for (int e = tid; e < HID_ * HID_; e += 256)
            ((float*)sm.ep.sW2)[e] = Wnext[e];
    }
    __syncthreads();

    if (tid < HID_) {
        float s = pool[0][tid] + pool[1][tid] + pool[2][tid] + pool[3][tid];
        partial[((size_t)b * 16 + blockIdx.x) * HID_ + tid] = s;
    }

    if (FUSE) {
        // hlinT_out[b][o][n] = bf16( sum_k h_s[n_local][k] * Wnext[k][o] )
        const int r_local = tid >> 2;          // 0..63
        const int obase = (tid & 3) * 8;       // 0,8,16,24
        float acc2[8];
#pragma unroll
        for (int o = 0; o < 8; ++o) acc2[o] = 0.f;
#pragma unroll 4
        for (int k = 0; k < HID_; ++k) {
            const float hv = sm.ep.h_s[r_local][k];
#pragma unroll
            for (int o = 0; o < 8; ++o) acc2[o] += hv * sm.ep.sW2[k][obase + o];
        }
        const int n = blockIdx.x * 64 + r_local;
        u16* op = hlinT_out + (size_t)b * HID_ * N_ + n;
#pragma unroll
        for (int o = 0; o < 8; ++o) op[(size_t)(obase + o) * N_] = f2bf(acc2[o]);
    }
}

// ---------------- finalize: out[b][l*32+o] = sum_t partial[l][b][t][o] ------
__global__ __launch_bounds__(256) void finalize_kernel(
    const float* __restrict__ partial,  // [4][B][16][HID]
    float* __restrict__ out)            // [B][4*HID]
{
    const int i = blockIdx.x * 256 + threadIdx.x;
    if (i >= B_ * 4 * HID_) return;
    const int b = i >> 7;
    const int rem = i & 127;
    const int l = rem >> 5;
    const int o = rem & 31;
    const float* p = partial + (((size_t)l * B_ + b) * 16) * HID_ + o;
    float s = 0.f;
#pragma unroll
    for (int t = 0; t < 16; ++t) s += p[t * HID_];
    out[i] = s;
}

extern "C" void kernel_launch(void* const* d_in, const int* in_sizes, int n_in,
                              void* d_out, int out_size, void* d_ws, size_t ws_size,
                              hipStream_t stream) {
    const float* x   = (const float*)d_in[0];
    const float* adj = (const float*)d_in[1];
    const float* W[4]  = {(const float*)d_in[2], (const float*)d_in[3],
                          (const float*)d_in[4], (const float*)d_in[5]};
    const float* bi[4] = {(const float*)d_in[6], (const float*)d_in[7],
                          (const float*)d_in[8], (const float*)d_in[9]};
    const float* al[4] = {(const float*)d_in[10], (const float*)d_in[11],
                          (const float*)d_in[12], (const float*)d_in[13]};
    float* out = (float*)d_out;

    const size_t adjb_bytes = (size_t)B_ * N_ * N_ * 2;
    const size_t hlin_bytes = (size_t)B_ * HID_ * N_ * 2;
    const size_t h_bytes    = (size_t)B_ * N_ * HID_ * 4;
    const size_t part_bytes = (size_t)4 * B_ * 16 * HID_ * 4;
    const bool full = ws_size >= adjb_bytes + 2 * hlin_bytes + part_bytes;

    const dim3 ga(16, 64);
    const int part_stride = B_ * 16 * HID_;

    if (full) {
        char* p = (char*)d_ws;
        u16* adjb  = (u16*)p;  p += adjb_bytes;
        u16* hlinA = (u16*)p;  p += hlin_bytes;
        u16* hlinB = (u16*)p;  p += hlin_bytes;
        float* partial = (float*)p;

        linear_kernel<IND_><<<256, 256, 0, stream>>>(x, W[0], hlinA);
        // layer 1: fp32 adj (nt) -> bf16 copy, fused linear2
        agg_kernel<1, 1><<<ga, 256, 0, stream>>>(adj, nullptr, adjb, hlinA, hlinB,
                                                 W[1], nullptr,
                                                 partial + 0, bi[0], al[0]);
        // layer 2: bf16 adj, fused linear3
        agg_kernel<0, 1><<<ga, 256, 0, stream>>>(nullptr, adjb, nullptr, hlinB, hlinA,
                                                 W[2], nullptr,
                                                 partial + (size_t)1 * part_stride,
                                                 bi[1], al[1]);
        // layer 3: bf16 adj, fused linear4
        agg_kernel<0, 1><<<ga, 256, 0, stream>>>(nullptr, adjb, nullptr, hlinA, hlinB,
                                                 W[3], nullptr,
                                                 partial + (size_t)2 * part_stride,
                                                 bi[2], al[2]);
        // layer 4: bf16 adj, no fuse (pool only)
        agg_kernel<0, 0><<<ga, 256, 0, stream>>>(nullptr, adjb, nullptr, hlinB, nullptr,
                                                 nullptr, nullptr,
                                                 partial + (size_t)3 * part_stride,
                                                 bi[3], al[3]);
    } else {
        // fallback: no bf16 adj copy, unfused linears via h buffer
        char* p = (char*)d_ws;
        u16*   hlinT   = (u16*)p;  p += hlin_bytes;
        float* h       = (float*)p; p += h_bytes;
        float* partial = (float*)p;

        linear_kernel<IND_><<<256, 256, 0, stream>>>(x, W[0], hlinT);
        agg_kernel<2, 0><<<ga, 256, 0, stream>>>(adj, nullptr, nullptr, hlinT, nullptr,
                                                 nullptr, h, partial + 0, bi[0], al[0]);
        for (int l = 1; l < 4; ++l) {
            linear_kernel<HID_><<<256, 256, 0, stream>>>(h, W[l], hlinT);
            agg_kernel<2, 0><<<ga, 256, 0, stream>>>(adj, nullptr, nullptr, hlinT, nullptr,
                                                     nullptr, h,
                                                     partial + (size_t)l * part_stride,
                                                     bi[l], al[l]);
        }
    }
    finalize_kernel<<<32, 256, 0, stream>>>(
        (const float*)((char*)d_ws + (full ? adjb_bytes + 2 * hlin_bytes
                                           : hlin_bytes + h_bytes)), out);
}

// Round 6
// 213.718 us; speedup vs baseline: 1.0190x; 1.0190x over previous
//
#include <hip/hip_runtime.h>
#include <hip/hip_bf16.h>

#define B_   64
#define N_   1024
#define IND_ 128
#define HID_ 32

typedef __attribute__((ext_vector_type(8))) short short8;
typedef __attribute__((ext_vector_type(4))) float f32x4;
typedef unsigned short u16;

static __device__ __forceinline__ u16 f2bf(float f) {
    union { __hip_bfloat16 h; u16 s; } u;
    u.h = __float2bfloat16(f);
    return u.s;
}
static __device__ __forceinline__ short8 cvt8(f32x4 v0, f32x4 v1) {
    union { short8 s; __hip_bfloat162 h[4]; } u;
    u.h[0] = __float22bfloat162_rn(float2{v0[0], v0[1]});
    u.h[1] = __float22bfloat162_rn(float2{v0[2], v0[3]});
    u.h[2] = __float22bfloat162_rn(float2{v1[0], v1[1]});
    u.h[3] = __float22bfloat162_rn(float2{v1[2], v1[3]});
    return u.s;
}

// ------------- streaming convert: adjb = bf16(adjf), fill-rate shaped -------
// Pure copy kernel: no MFMA/LDS/barriers coupling the loads -> deep ILP,
// saturates HBM like the harness fill (87% peak). nt loads keep the dead
// fp32 stream from evicting the bf16 copy we want L3-resident.
__global__ __launch_bounds__(256) void convert_kernel(
    const float* __restrict__ adjf, u16* __restrict__ adjb)
{
    const size_t total = (size_t)B_ * N_ * N_ / 8;      // short8 units
    const size_t stride = (size_t)gridDim.x * 256;
    for (size_t i = (size_t)blockIdx.x * 256 + threadIdx.x; i < total; i += stride) {
        const f32x4* src = (const f32x4*)adjf + i * 2;
        f32x4 v0 = __builtin_nontemporal_load(src);
        f32x4 v1 = __builtin_nontemporal_load(src + 1);
        ((short8*)adjb)[i] = cvt8(v0, v1);
    }
}

// ---------------- linear: hlinT[b][o][n] = sum_f in[b][n][f] * W[f][o] ------
template<int F>
__global__ __launch_bounds__(256) void linear_kernel(
    const float* __restrict__ in,    // [B][N][F] fp32
    const float* __restrict__ W,     // [F][HID]
    u16* __restrict__ outT)          // [B][HID][N] bf16
{
    __shared__ float sW[F][HID_];
    const int tid = threadIdx.x;
    for (int e = tid; e < F * HID_; e += 256) sW[e / HID_][e % HID_] = W[e];
    __syncthreads();

    const int b = blockIdx.x >> 2;
    const int n = ((blockIdx.x & 3) << 8) + tid;
    const f32x4* row4 = (const f32x4*)(in + ((size_t)b * N_ + n) * F);

    float acc[HID_];
#pragma unroll
    for (int o = 0; o < HID_; ++o) acc[o] = 0.f;

#pragma unroll 4
    for (int f4 = 0; f4 < F / 4; ++f4) {
        f32x4 xv = row4[f4];
#pragma unroll
        for (int j = 0; j < 4; ++j) {
#pragma unroll
            for (int o = 0; o < HID_; ++o) acc[o] += xv[j] * sW[f4 * 4 + j][o];
        }
    }
    u16* op = outT + (size_t)b * HID_ * N_ + n;
#pragma unroll
    for (int o = 0; o < HID_; ++o) op[o * N_] = f2bf(acc[o]);
}

// ---------------- aggregation: h = PReLU(adj @ hlin + bias); optional fused
// next-layer linear: hlinT_out = (h @ Wnext)^T in bf16.
// Geometry: 1024 blocks (16 x-tiles x 64 batches), 4 waves/block, 16 rows/wave
//   -> 4096 waves (4/SIMD), ~34KB LDS -> 4 blocks/CU.
// MODE 0: read bf16 adj (L3-hot); MODE 2: read fp32 adj, h to global (fallback)
template<int MODE, int FUSE>
__global__ __launch_bounds__(256) void agg_kernel(
    const float* __restrict__ adjf,     // [B][N][N] fp32   (MODE 2)
    const u16*  __restrict__ adjb_in,   // [B][N][N] bf16   (MODE 0)
    const u16*  __restrict__ hlinT_in,  // [B][HID][N] bf16
    u16*        __restrict__ hlinT_out, // [B][HID][N] bf16 (FUSE)
    const float* __restrict__ Wnext,    // [HID][HID]       (FUSE)
    float*      __restrict__ h,         // [B][N][HID] fp32 (MODE 2 only)
    float*      __restrict__ partial,   // [B][16][HID] (this layer's slice)
    const float* __restrict__ bias,     // [HID]
    const float* __restrict__ alpha_p)  // [1]
{
    union Smem {
        u16 sB[HID_][512 + 8];                       // 33,280 B (K-chunk of B)
        struct { float h_s[64][33]; float sW2[HID_][HID_]; } ep;  // 12,544 B
    };
    __shared__ Smem sm;
    __shared__ float pool[4][HID_];

    const int tid = threadIdx.x;
    const int b = blockIdx.y;
    const int wid = tid >> 6, lane = tid & 63;
    const int r16 = lane & 15, g = lane >> 4;
    const int koff = g * 8;
    const int rowbase = blockIdx.x * 64 + wid * 16;
    const int row0 = rowbase + r16;
    const size_t adj_b = (size_t)b * N_ * N_;
    const u16* srcB = hlinT_in + (size_t)b * HID_ * N_;

    const u16*  pa = adjb_in ? adjb_in + adj_b + (size_t)row0 * N_ + koff : nullptr;
    const float* pf = adjf   ? adjf    + adj_b + (size_t)row0 * N_ + koff : nullptr;

    f32x4 acc[2] = {};

    for (int c = 0; c < 2; ++c) {
        if (c) __syncthreads();          // previous chunk's ds_reads complete
        // stage B chunk: 32 rows x 512 cols bf16 (L2-hot source)
        for (int i = tid; i < 2048; i += 256) {
            const int row = i >> 6;
            const int kv = (i & 63) << 3;
            *(short8*)&sm.sB[row][kv] =
                *(const short8*)(srcB + (size_t)row * N_ + (c << 9) + kv);
        }
        __syncthreads();

#pragma unroll 8
        for (int kk = 0; kk < 512; kk += 32) {
            const int k0 = (c << 9) + kk;
            short8 a0;
            if (MODE == 0) {
                a0 = *(const short8*)(pa + k0);
            } else {
                f32x4 v0 = __builtin_nontemporal_load((const f32x4*)(pf + k0));
                f32x4 v1 = __builtin_nontemporal_load((const f32x4*)(pf + k0) + 1);
                a0 = cvt8(v0, v1);
            }
            short8 b0 = *(const short8*)&sm.sB[r16][kk + koff];
            short8 b1 = *(const short8*)&sm.sB[16 + r16][kk + koff];
            acc[0] = __builtin_amdgcn_mfma_f32_16x16x32_bf16(a0, b0, acc[0], 0, 0, 0);
            acc[1] = __builtin_amdgcn_mfma_f32_16x16x32_bf16(a0, b1, acc[1], 0, 0, 0);
        }
    }

    // bias + PReLU in registers, per-column pool partials
    const float alpha = *alpha_p;
    float v[2][4];
    float ps[2];
#pragma unroll
    for (int ct = 0; ct < 2; ++ct) {
        const float bv = bias[ct * 16 + r16];
        ps[ct] = 0.f;
#pragma unroll
        for (int r = 0; r < 4; ++r) {
            float x = acc[ct][r] + bv;
            x = (x >= 0.f) ? x : alpha * x;
            v[ct][r] = x;
            ps[ct] += x;
        }
    }

    __syncthreads();                     // sB dead; ep space usable

#pragma unroll
    for (int ct = 0; ct < 2; ++ct) {
        const int col = ct * 16 + r16;
        float p = ps[ct];
        p += __shfl_xor(p, 16, 64);
        p += __shfl_xor(p, 32, 64);
        if (lane < 16) pool[wid][col] = p;
        if (FUSE) {
#pragma unroll
            for (int r = 0; r < 4; ++r)
                sm.ep.h_s[wid * 16 + g * 4 + r][col] = v[ct][r];
        }
        if (MODE == 2) {
#pragma unroll
            for (int r = 0; r < 4; ++r) {
                const int row = rowbase + g * 4 + r;
                h[((size_t)b * N_ + row) * HID_ + col] = v[ct][r];
            }
        }
    }
    if (FUSE) {
        for (int e = tid; e < HID_ * HID_; e += 256)
            ((float*)sm.ep.sW2)[e] = Wnext[e];
    }
    __syncthreads();

    if (tid < HID_) {
        float s = pool[0][tid] + pool[1][tid] + pool[2][tid] + pool[3][tid];
        partial[((size_t)b * 16 + blockIdx.x) * HID_ + tid] = s;
    }

    if (FUSE) {
        // hlinT_out[b][o][n] = bf16( sum_k h_s[n_local][k] * Wnext[k][o] )
        const int r_local = tid >> 2;          // 0..63
        const int obase = (tid & 3) * 8;       // 0,8,16,24
        float acc2[8];
#pragma unroll
        for (int o = 0; o < 8; ++o) acc2[o] = 0.f;
#pragma unroll 4
        for (int k = 0; k < HID_; ++k) {
            const float hv = sm.ep.h_s[r_local][k];
#pragma unroll
            for (int o = 0; o < 8; ++o) acc2[o] += hv * sm.ep.sW2[k][obase + o];
        }
        const int n = blockIdx.x * 64 + r_local;
        u16* op = hlinT_out + (size_t)b * HID_ * N_ + n;
#pragma unroll
        for (int o = 0; o < 8; ++o) op[(size_t)(obase + o) * N_] = f2bf(acc2[o]);
    }
}

// ---------------- finalize: out[b][l*32+o] = sum_t partial[l][b][t][o] ------
__global__ __launch_bounds__(256) void finalize_kernel(
    const float* __restrict__ partial,  // [4][B][16][HID]
    float* __restrict__ out)            // [B][4*HID]
{
    const int i = blockIdx.x * 256 + threadIdx.x;
    if (i >= B_ * 4 * HID_) return;
    const int b = i >> 7;
    const int rem = i & 127;
    const int l = rem >> 5;
    const int o = rem & 31;
    const float* p = partial + (((size_t)l * B_ + b) * 16) * HID_ + o;
    float s = 0.f;
#pragma unroll
    for (int t = 0; t < 16; ++t) s += p[t * HID_];
    out[i] = s;
}

extern "C" void kernel_launch(void* const* d_in, const int* in_sizes, int n_in,
                              void* d_out, int out_size, void* d_ws, size_t ws_size,
                              hipStream_t stream) {
    const float* x   = (const float*)d_in[0];
    const float* adj = (const float*)d_in[1];
    const float* W[4]  = {(const float*)d_in[2], (const float*)d_in[3],
                          (const float*)d_in[4], (const float*)d_in[5]};
    const float* bi[4] = {(const float*)d_in[6], (const float*)d_in[7],
                          (const float*)d_in[8], (const float*)d_in[9]};
    const float* al[4] = {(const float*)d_in[10], (const float*)d_in[11],
                          (const float*)d_in[12], (const float*)d_in[13]};
    float* out = (float*)d_out;

    const size_t adjb_bytes = (size_t)B_ * N_ * N_ * 2;
    const size_t hlin_bytes = (size_t)B_ * HID_ * N_ * 2;
    const size_t h_bytes    = (size_t)B_ * N_ * HID_ * 4;
    const size_t part_bytes = (size_t)4 * B_ * 16 * HID_ * 4;
    const bool full = ws_size >= adjb_bytes + 2 * hlin_bytes + part_bytes;

    const dim3 ga(16, 64);
    const int part_stride = B_ * 16 * HID_;

    if (full) {
        char* p = (char*)d_ws;
        u16* adjb  = (u16*)p;  p += adjb_bytes;
        u16* hlinA = (u16*)p;  p += hlin_bytes;
        u16* hlinB = (u16*)p;  p += hlin_bytes;
        float* partial = (float*)p;

        // streaming fp32->bf16 conversion at fill-rate (runs concurrent with linear1)
        convert_kernel<<<2048, 256, 0, stream>>>(adj, adjb);
        linear_kernel<IND_><<<256, 256, 0, stream>>>(x, W[0], hlinA);

        // 4 GCN layers, all on the L3-hot bf16 adjacency
        agg_kernel<0, 1><<<ga, 256, 0, stream>>>(nullptr, adjb, hlinA, hlinB,
                                                 W[1], nullptr,
                                                 partial + 0, bi[0], al[0]);
        agg_kernel<0, 1><<<ga, 256, 0, stream>>>(nullptr, adjb, hlinB, hlinA,
                                                 W[2], nullptr,
                                                 partial + (size_t)1 * part_stride,
                                                 bi[1], al[1]);
        agg_kernel<0, 1><<<ga, 256, 0, stream>>>(nullptr, adjb, hlinA, hlinB,
                                                 W[3], nullptr,
                                                 partial + (size_t)2 * part_stride,
                                                 bi[2], al[2]);
        agg_kernel<0, 0><<<ga, 256, 0, stream>>>(nullptr, adjb, hlinB, nullptr,
                                                 nullptr, nullptr,
                                                 partial + (size_t)3 * part_stride,
                                                 bi[3], al[3]);
    } else {
        // fallback: no bf16 adj copy, unfused linears via h buffer
        char* p = (char*)d_ws;
        u16*   hlinT   = (u16*)p;  p += hlin_bytes;
        float* h       = (float*)p; p += h_bytes;
        float* partial = (float*)p;

        linear_kernel<IND_><<<256, 256, 0, stream>>>(x, W[0], hlinT);
        agg_kernel<2, 0><<<ga, 256, 0, stream>>>(adj, nullptr, hlinT, nullptr,
                                                 nullptr, h, partial + 0, bi[0], al[0]);
        for (int l = 1; l < 4; ++l) {
            linear_kernel<HID_><<<256, 256, 0, stream>>>(h, W[l], hlinT);
            agg_kernel<2, 0><<<ga, 256, 0, stream>>>(adj, nullptr, hlinT, nullptr,
                                                     nullptr, h,
                                                     partial + (size_t)l * part_stride,
                                                     bi[l], al[l]);
        }
    }
    finalize_kernel<<<32, 256, 0, stream>>>(
        (const float*)((char*)d_ws + (full ? adjb_bytes + 2 * hlin_bytes
                                           : hlin_bytes + h_bytes)), out);
}

// Round 7
// 212.506 us; speedup vs baseline: 1.0248x; 1.0057x over previous
//
#include <hip/hip_runtime.h>
#include <hip/hip_bf16.h>

#define B_   64
#define N_   1024
#define IND_ 128
#define HID_ 32

typedef __attribute__((ext_vector_type(8))) short short8;
typedef __attribute__((ext_vector_type(4))) float f32x4;
typedef unsigned short u16;

static __device__ __forceinline__ u16 f2bf(float f) {
    union { __hip_bfloat16 h; u16 s; } u;
    u.h = __float2bfloat16(f);
    return u.s;
}
static __device__ __forceinline__ short8 cvt8(f32x4 v0, f32x4 v1) {
    union { short8 s; __hip_bfloat162 h[4]; } u;
    u.h[0] = __float22bfloat162_rn(float2{v0[0], v0[1]});
    u.h[1] = __float22bfloat162_rn(float2{v0[2], v0[3]});
    u.h[2] = __float22bfloat162_rn(float2{v1[0], v1[1]});
    u.h[3] = __float22bfloat162_rn(float2{v1[2], v1[3]});
    return u.s;
}

// ------------- streaming convert: fp32 adj -> bf16 adjT in FRAGMENT-TILED
// layout. Tile t = (b, rt, ki) stores the 16x32 A-fragment for MFMA wave
// consumption: element [lane][0..7] = adj[b][rt*16 + (lane&15)][ki*32 +
// (lane>>4)*8 + j]. Agg A-loads then become contiguous 1KB per wave-issue
// instead of 16 scattered 64-B segments (which measured ~4.5 TB/s).
__global__ __launch_bounds__(256) void convert_tile_kernel(
    const float* __restrict__ adjf, u16* __restrict__ adjT)
{
    const int wslot = blockIdx.x * 4 + (threadIdx.x >> 6);   // 0..8191
    const int lane = threadIdx.x & 63;
    const int r = lane & 15, g = lane >> 4;
    const int t0 = wslot * 16;              // 16 consecutive tiles per wave
    const int b  = t0 >> 11;                // 2048 tiles per batch
    const int rt = (t0 >> 5) & 63;
    const int k0base = (t0 & 31) * 32;      // element col base (0 or 512)

    const float* src = adjf + ((size_t)b * N_ + rt * 16 + r) * N_ + k0base + g * 8;
    u16* dst = adjT + (size_t)t0 * 512 + lane * 8;

#pragma unroll 4
    for (int j = 0; j < 16; ++j) {
        // nt: dead fp32 stream must not evict the bf16 copy from L2/L3
        f32x4 v0 = __builtin_nontemporal_load((const f32x4*)(src + j * 32));
        f32x4 v1 = __builtin_nontemporal_load((const f32x4*)(src + j * 32) + 1);
        *(short8*)(dst + (size_t)j * 512) = cvt8(v0, v1);
    }
}

// ---------------- linear: hlinT[b][o][n] = sum_f in[b][n][f] * W[f][o] ------
template<int F>
__global__ __launch_bounds__(256) void linear_kernel(
    const float* __restrict__ in,    // [B][N][F] fp32
    const float* __restrict__ W,     // [F][HID]
    u16* __restrict__ outT)          // [B][HID][N] bf16
{
    __shared__ float sW[F][HID_];
    const int tid = threadIdx.x;
    for (int e = tid; e < F * HID_; e += 256) sW[e / HID_][e % HID_] = W[e];
    __syncthreads();

    const int b = blockIdx.x >> 2;
    const int n = ((blockIdx.x & 3) << 8) + tid;
    const f32x4* row4 = (const f32x4*)(in + ((size_t)b * N_ + n) * F);

    float acc[HID_];
#pragma unroll
    for (int o = 0; o < HID_; ++o) acc[o] = 0.f;

#pragma unroll 4
    for (int f4 = 0; f4 < F / 4; ++f4) {
        f32x4 xv = row4[f4];
#pragma unroll
        for (int j = 0; j < 4; ++j) {
#pragma unroll
            for (int o = 0; o < HID_; ++o) acc[o] += xv[j] * sW[f4 * 4 + j][o];
        }
    }
    u16* op = outT + (size_t)b * HID_ * N_ + n;
#pragma unroll
    for (int o = 0; o < HID_; ++o) op[o * N_] = f2bf(acc[o]);
}

// ---------------- aggregation: h = PReLU(adj @ hlin + bias); optional fused
// next-layer linear: hlinT_out = (h @ Wnext)^T in bf16.
// Geometry: 1024 blocks (16 x-tiles x 64 batches), 4 waves/block, 16 rows/wave
//   -> 4096 waves (4/SIMD), ~34KB LDS -> 4 blocks/CU.
// MODE 0: read fragment-tiled bf16 adjT (contiguous 1KB wave-issues, L3-hot);
// MODE 2: read row-major fp32 adj, h to global (fallback path)
template<int MODE, int FUSE>
__global__ __launch_bounds__(256) void agg_kernel(
    const float* __restrict__ adjf,     // [B][N][N] fp32      (MODE 2)
    const u16*  __restrict__ adjT,      // [B][2048][512] bf16 (MODE 0, tiled)
    const u16*  __restrict__ hlinT_in,  // [B][HID][N] bf16
    u16*        __restrict__ hlinT_out, // [B][HID][N] bf16 (FUSE)
    const float* __restrict__ Wnext,    // [HID][HID]       (FUSE)
    float*      __restrict__ h,         // [B][N][HID] fp32 (MODE 2 only)
    float*      __restrict__ partial,   // [B][16][HID] (this layer's slice)
    const float* __restrict__ bias,     // [HID]
    const float* __restrict__ alpha_p)  // [1]
{
    union Smem {
        u16 sB[HID_][512 + 8];                       // 33,280 B (K-chunk of B)
        struct { float h_s[64][33]; float sW2[HID_][HID_]; } ep;  // 12,544 B
    };
    __shared__ Smem sm;
    __shared__ float pool[4][HID_];

    const int tid = threadIdx.x;
    const int b = blockIdx.y;
    const int wid = tid >> 6, lane = tid & 63;
    const int r16 = lane & 15, g = lane >> 4;
    const int koff = g * 8;
    const int rowbase = blockIdx.x * 64 + wid * 16;
    const int row0 = rowbase + r16;
    const u16* srcB = hlinT_in + (size_t)b * HID_ * N_;

    // tiled A base: tile index = b*2048 + (rowbase/16)*32 + ki
    const u16* pa = adjT
        ? adjT + ((size_t)b * 2048 + (size_t)(blockIdx.x * 4 + wid) * 32) * 512 + lane * 8
        : nullptr;
    const float* pf = adjf
        ? adjf + ((size_t)b * N_ + row0) * N_ + koff
        : nullptr;

    f32x4 acc[2] = {};

    for (int c = 0; c < 2; ++c) {
        if (c) __syncthreads();          // previous chunk's ds_reads complete
        // stage B chunk: 32 rows x 512 cols bf16 (L2-hot source)
        for (int i = tid; i < 2048; i += 256) {
            const int row = i >> 6;
            const int kv = (i & 63) << 3;
            *(short8*)&sm.sB[row][kv] =
                *(const short8*)(srcB + (size_t)row * N_ + (c << 9) + kv);
        }
        __syncthreads();

#pragma unroll 8
        for (int kk = 0; kk < 512; kk += 32) {
            short8 a0;
            if (MODE == 0) {
                const int ki = c * 16 + (kk >> 5);
                a0 = *(const short8*)(pa + (size_t)ki * 512);
            } else {
                const int k0 = (c << 9) + kk;
                f32x4 v0 = __builtin_nontemporal_load((const f32x4*)(pf + k0));
                f32x4 v1 = __builtin_nontemporal_load((const f32x4*)(pf + k0) + 1);
                a0 = cvt8(v0, v1);
            }
            short8 b0 = *(const short8*)&sm.sB[r16][kk + koff];
            short8 b1 = *(const short8*)&sm.sB[16 + r16][kk + koff];
            acc[0] = __builtin_amdgcn_mfma_f32_16x16x32_bf16(a0, b0, acc[0], 0, 0, 0);
            acc[1] = __builtin_amdgcn_mfma_f32_16x16x32_bf16(a0, b1, acc[1], 0, 0, 0);
        }
    }

    // bias + PReLU in registers, per-column pool partials
    const float alpha = *alpha_p;
    float v[2][4];
    float ps[2];
#pragma unroll
    for (int ct = 0; ct < 2; ++ct) {
        const float bv = bias[ct * 16 + r16];
        ps[ct] = 0.f;
#pragma unroll
        for (int r = 0; r < 4; ++r) {
            float x = acc[ct][r] + bv;
            x = (x >= 0.f) ? x : alpha * x;
            v[ct][r] = x;
            ps[ct] += x;
        }
    }

    __syncthreads();                     // sB dead; ep space usable

#pragma unroll
    for (int ct = 0; ct < 2; ++ct) {
        const int col = ct * 16 + r16;
        float p = ps[ct];
        p += __shfl_xor(p, 16, 64);
        p += __shfl_xor(p, 32, 64);
        if (lane < 16) pool[wid][col] = p;
        if (FUSE) {
#pragma unroll
            for (int r = 0; r < 4; ++r)
                sm.ep.h_s[wid * 16 + g * 4 + r][col] = v[ct][r];
        }
        if (MODE == 2) {
#pragma unroll
            for (int r = 0; r < 4; ++r) {
                const int row = rowbase + g * 4 + r;
                h[((size_t)b * N_ + row) * HID_ + col] = v[ct][r];
            }
        }
    }
    if (FUSE) {
        for (int e = tid; e < HID_ * HID_; e += 256)
            ((float*)sm.ep.sW2)[e] = Wnext[e];
    }
    __syncthreads();

    if (tid < HID_) {
        float s = pool[0][tid] + pool[1][tid] + pool[2][tid] + pool[3][tid];
        partial[((size_t)b * 16 + blockIdx.x) * HID_ + tid] = s;
    }

    if (FUSE) {
        // hlinT_out[b][o][n] = bf16( sum_k h_s[n_local][k] * Wnext[k][o] )
        const int r_local = tid >> 2;          // 0..63
        const int obase = (tid & 3) * 8;       // 0,8,16,24
        float acc2[8];
#pragma unroll
        for (int o = 0; o < 8; ++o) acc2[o] = 0.f;
#pragma unroll 4
        for (int k = 0; k < HID_; ++k) {
            const float hv = sm.ep.h_s[r_local][k];
#pragma unroll
            for (int o = 0; o < 8; ++o) acc2[o] += hv * sm.ep.sW2[k][obase + o];
        }
        const int n = blockIdx.x * 64 + r_local;
        u16* op = hlinT_out + (size_t)b * HID_ * N_ + n;
#pragma unroll
        for (int o = 0; o < 8; ++o) op[(size_t)(obase + o) * N_] = f2bf(acc2[o]);
    }
}

// ---------------- finalize: out[b][l*32+o] = sum_t partial[l][b][t][o] ------
__global__ __launch_bounds__(256) void finalize_kernel(
    const float* __restrict__ partial,  // [4][B][16][HID]
    float* __restrict__ out)            // [B][4*HID]
{
    const int i = blockIdx.x * 256 + threadIdx.x;
    if (i >= B_ * 4 * HID_) return;
    const int b = i >> 7;
    const int rem = i & 127;
    const int l = rem >> 5;
    const int o = rem & 31;
    const float* p = partial + (((size_t)l * B_ + b) * 16) * HID_ + o;
    float s = 0.f;
#pragma unroll
    for (int t = 0; t < 16; ++t) s += p[t * HID_];
    out[i] = s;
}

extern "C" void kernel_launch(void* const* d_in, const int* in_sizes, int n_in,
                              void* d_out, int out_size, void* d_ws, size_t ws_size,
                              hipStream_t stream) {
    const float* x   = (const float*)d_in[0];
    const float* adj = (const float*)d_in[1];
    const float* W[4]  = {(const float*)d_in[2], (const float*)d_in[3],
                          (const float*)d_in[4], (const float*)d_in[5]};
    const float* bi[4] = {(const float*)d_in[6], (const float*)d_in[7],
                          (const float*)d_in[8], (const float*)d_in[9]};
    const float* al[4] = {(const float*)d_in[10], (const float*)d_in[11],
                          (const float*)d_in[12], (const float*)d_in[13]};
    float* out = (float*)d_out;

    const size_t adjb_bytes = (size_t)B_ * N_ * N_ * 2;
    const size_t hlin_bytes = (size_t)B_ * HID_ * N_ * 2;
    const size_t h_bytes    = (size_t)B_ * N_ * HID_ * 4;
    const size_t part_bytes = (size_t)4 * B_ * 16 * HID_ * 4;
    const bool full = ws_size >= adjb_bytes + 2 * hlin_bytes + part_bytes;

    const dim3 ga(16, 64);
    const int part_stride = B_ * 16 * HID_;

    if (full) {
        char* p = (char*)d_ws;
        u16* adjT  = (u16*)p;  p += adjb_bytes;
        u16* hlinA = (u16*)p;  p += hlin_bytes;
        u16* hlinB = (u16*)p;  p += hlin_bytes;
        float* partial = (float*)p;

        // streaming fp32->bf16 tiled conversion (concurrent with linear1)
        convert_tile_kernel<<<2048, 256, 0, stream>>>(adj, adjT);
        linear_kernel<IND_><<<256, 256, 0, stream>>>(x, W[0], hlinA);

        // 4 GCN layers, all on the L3-hot fragment-tiled bf16 adjacency
        agg_kernel<0, 1><<<ga, 256, 0, stream>>>(nullptr, adjT, hlinA, hlinB,
                                                 W[1], nullptr,
                                                 partial + 0, bi[0], al[0]);
        agg_kernel<0, 1><<<ga, 256, 0, stream>>>(nullptr, adjT, hlinB, hlinA,
                                                 W[2], nullptr,
                                                 partial + (size_t)1 * part_stride,
                                                 bi[1], al[1]);
        agg_kernel<0, 1><<<ga, 256, 0, stream>>>(nullptr, adjT, hlinA, hlinB,
                                                 W[3], nullptr,
                                                 partial + (size_t)2 * part_stride,
                                                 bi[2], al[2]);
        agg_kernel<0, 0><<<ga, 256, 0, stream>>>(nullptr, adjT, hlinB, nullptr,
                                                 nullptr, nullptr,
                                                 partial + (size_t)3 * part_stride,
                                                 bi[3], al[3]);
    } else {
        // fallback: no bf16 adj copy, unfused linears via h buffer
        char* p = (char*)d_ws;
        u16*   hlinT   = (u16*)p;  p += hlin_bytes;
        float* h       = (float*)p; p += h_bytes;
        float* partial = (float*)p;

        linear_kernel<IND_><<<256, 256, 0, stream>>>(x, W[0], hlinT);
        agg_kernel<2, 0><<<ga, 256, 0, stream>>>(adj, nullptr, hlinT, nullptr,
                                                 nullptr, h, partial + 0, bi[0], al[0]);
        for (int l = 1; l < 4; ++l) {
            linear_kernel<HID_><<<256, 256, 0, stream>>>(h, W[l], hlinT);
            agg_kernel<2, 0><<<ga, 256, 0, stream>>>(adj, nullptr, hlinT, nullptr,
                                                     nullptr, h,
                                                     partial + (size_t)l * part_stride,
                                                     bi[l], al[l]);
        }
    }
    finalize_kernel<<<32, 256, 0, stream>>>(
        (const float*)((char*)d_ws + (full ? adjb_bytes + 2 * hlin_bytes
                                           : hlin_bytes + h_bytes)), out);
}